// Round 9
// baseline (2850.857 us; speedup 1.0000x reference)
//
#include <hip/hip_runtime.h>
#include <hip/hip_bf16.h>
#include <math.h>

// Problem constants (match reference)
constexpr int B_  = 64;
constexpr int L_  = 512;
constexpr int D_  = 384;
constexpr int H_  = 12;
constexpr int DH_ = 32;
constexpr int NL_ = 6;
constexpr int FF_ = 1536;
constexpr int CH_ = 64;
constexpr int MT  = B_ * L_;       // 32768 tokens
constexpr int DD  = D_ * D_;       // 147456

typedef float f32x4 __attribute__((ext_vector_type(4)));
typedef short s16x8 __attribute__((ext_vector_type(8)));
typedef short s16x4 __attribute__((ext_vector_type(4)));

// round-to-nearest-even f32 -> bf16 bits
__device__ __forceinline__ short f2bf(float f) {
    unsigned u = __float_as_uint(f);
    unsigned r = (u + 0x7fffu + ((u >> 16) & 1u)) >> 16;
    return (short)r;
}
__device__ __forceinline__ float bf2f(short s) {
    unsigned u = ((unsigned)(unsigned short)s) << 16;
    return __uint_as_float(u);
}

// ---------------------------------------------------------------------------
// Weight conversion: fp32 -> bf16, 8 elems/thread
// ---------------------------------------------------------------------------
__global__ void cvt_kernel(const float* __restrict__ src, short* __restrict__ dst, int n8) {
    int i = blockIdx.x * 256 + threadIdx.x;
    if (i >= n8) return;
    const float4 lo = *(const float4*)(src + (size_t)i * 8);
    const float4 hi = *(const float4*)(src + (size_t)i * 8 + 4);
    s16x8 t;
    t[0] = f2bf(lo.x); t[1] = f2bf(lo.y); t[2] = f2bf(lo.z); t[3] = f2bf(lo.w);
    t[4] = f2bf(hi.x); t[5] = f2bf(hi.y); t[6] = f2bf(hi.z); t[7] = f2bf(hi.w);
    *(s16x8*)(dst + (size_t)i * 8) = t;
}

// q/k/v/g weights -> interleaved [layer][4][DD] bf16
__global__ void cvt4_kernel(const float* __restrict__ q, const float* __restrict__ k,
                            const float* __restrict__ v, const float* __restrict__ g,
                            short* __restrict__ dst) {
    int i = blockIdx.x * 256 + threadIdx.x;   // over NL*DD/8
    if (i >= NL_ * DD / 8) return;
    const int l = i / (DD / 8), r = i - l * (DD / 8);
    const float* srcs[4] = {q, k, v, g};
#pragma unroll
    for (int w = 0; w < 4; w++) {
        const float4 lo = *(const float4*)(srcs[w] + (size_t)i * 8);
        const float4 hi = *(const float4*)(srcs[w] + (size_t)i * 8 + 4);
        s16x8 t;
        t[0] = f2bf(lo.x); t[1] = f2bf(lo.y); t[2] = f2bf(lo.z); t[3] = f2bf(lo.w);
        t[4] = f2bf(hi.x); t[5] = f2bf(hi.y); t[6] = f2bf(hi.z); t[7] = f2bf(hi.w);
        *(s16x8*)(dst + ((size_t)(l * 4 + w) * DD) + (size_t)r * 8) = t;
    }
}

// ---------------------------------------------------------------------------
// Embedding + LayerNorm, wave-per-token (4 tokens / 256-thread block).
// Writes fp32 x and bf16 shadow xb.
// ---------------------------------------------------------------------------
__global__ __launch_bounds__(256) void embed_ln_kernel(
        const int* __restrict__ ids, const float* __restrict__ wemb,
        const float* __restrict__ pemb, const float* __restrict__ temb,
        const float* __restrict__ w, const float* __restrict__ b,
        float* __restrict__ out, short* __restrict__ outb) {
    const int t    = blockIdx.x * 4 + (threadIdx.x >> 6);
    const int lane = threadIdx.x & 63;
    const int l    = t % L_;
    const size_t ro = (size_t)t * D_;
    const size_t wo = (size_t)ids[t] * D_;
    const size_t po = (size_t)l * D_;

    float v[6];
    float s = 0.f;
#pragma unroll
    for (int j = 0; j < 6; j++) {
        const int d = j * 64 + lane;
        v[j] = wemb[wo + d] + pemb[po + d] + temb[d];
        s += v[j];
    }
#pragma unroll
    for (int o = 32; o > 0; o >>= 1) s += __shfl_xor(s, o);
    const float m = s * (1.f / D_);
    float s2 = 0.f;
#pragma unroll
    for (int j = 0; j < 6; j++) { v[j] -= m; s2 += v[j] * v[j]; }
#pragma unroll
    for (int o = 32; o > 0; o >>= 1) s2 += __shfl_xor(s2, o);
    const float r = rsqrtf(s2 * (1.f / D_) + 1e-12f);
#pragma unroll
    for (int j = 0; j < 6; j++) {
        const int d = j * 64 + lane;
        const float o = v[j] * r * w[d] + b[d];
        out[ro + d]  = o;
        outb[ro + d] = f2bf(o);
    }
}

// ---------------------------------------------------------------------------
// x = LN(x + y), y is bf16; bf16 shadow xb. Wave-per-token, no LDS/barriers.
// ---------------------------------------------------------------------------
__global__ __launch_bounds__(256) void ln_res_kernel(
        const short* __restrict__ y, float* __restrict__ x, short* __restrict__ xb,
        const float* __restrict__ w, const float* __restrict__ b) {
    const int t    = blockIdx.x * 4 + (threadIdx.x >> 6);
    const int lane = threadIdx.x & 63;
    const size_t ro = (size_t)t * D_;

    float v[6];
    float s = 0.f;
#pragma unroll
    for (int j = 0; j < 6; j++) {
        const int d = j * 64 + lane;
        v[j] = x[ro + d] + bf2f(y[ro + d]);
        s += v[j];
    }
#pragma unroll
    for (int o = 32; o > 0; o >>= 1) s += __shfl_xor(s, o);
    const float m = s * (1.f / D_);
    float s2 = 0.f;
#pragma unroll
    for (int j = 0; j < 6; j++) { v[j] -= m; s2 += v[j] * v[j]; }
#pragma unroll
    for (int o = 32; o > 0; o >>= 1) s2 += __shfl_xor(s2, o);
    const float r = rsqrtf(s2 * (1.f / D_) + 1e-12f);
#pragma unroll
    for (int j = 0; j < 6; j++) {
        const int d = j * 64 + lane;
        const float o = v[j] * r * w[d] + b[d];
        x[ro + d]  = o;
        xb[ro + d] = f2bf(o);
    }
}

// ---------------------------------------------------------------------------
// wfac[l][which] = mean(sigmoid(decay))^64   (12 blocks, 384 threads)
// ---------------------------------------------------------------------------
__global__ void wfac_kernel(const float* __restrict__ fdec, const float* __restrict__ sdec,
                            float* __restrict__ wf) {
    const int l     = blockIdx.x >> 1;
    const int which = blockIdx.x & 1;
    const float* p  = (which ? sdec : fdec) + (size_t)l * H_ * DH_;
    float v = 1.f / (1.f + expf(-p[threadIdx.x]));
    __shared__ float red[6];
#pragma unroll
    for (int o = 32; o > 0; o >>= 1) v += __shfl_down(v, o);
    if ((threadIdx.x & 63) == 0) red[threadIdx.x >> 6] = v;
    __syncthreads();
    if (threadIdx.x == 0) {
        float s = 0.f;
        for (int i = 0; i < 6; i++) s += red[i];
        float m = s / (float)(H_ * DH_);
        for (int i = 0; i < 6; i++) m = m * m;   // m^64
        wf[l * 2 + which] = m;
    }
}

// ---------------------------------------------------------------------------
// Depthwise conv1d (k=4, pad=2, truncate to L) + bias + SiLU. bf16 in/out.
// Vectorized: each thread owns 8 consecutive d (short8 loads/stores).
// ---------------------------------------------------------------------------
__global__ __launch_bounds__(256) void conv_silu_kernel(
        const short* __restrict__ xb, const float* __restrict__ cw,
        const float* __restrict__ cb, short* __restrict__ out) {
    const int i8 = blockIdx.x * 256 + threadIdx.x;   // over MT*D/8
    const int d8 = (i8 * 8) % D_;
    const int bl = (i8 * 8) / D_;
    const int l  = bl % L_;

    float acc[8];
#pragma unroll
    for (int jj = 0; jj < 8; jj++) acc[jj] = cb[d8 + jj];

    const short* xrow = xb + (size_t)(bl - l) * D_ + d8;
#pragma unroll
    for (int j = 0; j < 4; j++) {
        const int t = l + j - 2;
        if (t >= 0 && t < L_) {
            const s16x8 xv = *(const s16x8*)(xrow + (size_t)t * D_);
#pragma unroll
            for (int jj = 0; jj < 8; jj++)
                acc[jj] = fmaf(bf2f(xv[jj]), cw[(d8 + jj) * 4 + j], acc[jj]);
        }
    }
    s16x8 o;
#pragma unroll
    for (int jj = 0; jj < 8; jj++) {
        const float sv = acc[jj] / (1.f + expf(-acc[jj]));   // SiLU
        o[jj] = f2bf(sv);
    }
    *(s16x8*)(out + (size_t)i8 * 8) = o;
}

// ---------------------------------------------------------------------------
// MFMA bf16 GEMM: C[m,n] = bf16( act( sum_k A[m,k]*W[n,k] + bias[n] ) )
// A: (M,K) bf16; W: (N,K) bf16 row-major. 128x128 tile, BK=32,
// 256 thr = 4 waves (2x2), 4x4 16x16x32 frags/wave.
// REGISTER-staged (safe path): global_load_dwordx4 -> regs -> ds_write_b128,
// double-buffered, loads for tile kt+1 issued before MFMA of tile kt.
// XOR swizzle applied on the LDS WRITE address; fragment reads apply the
// same involution (content at slot r*4+(kqr^swz(r)) is K-quarter kqr).
// blockIdx.z picks weight/output slice via zsW / zsC (element strides).
// ---------------------------------------------------------------------------
template <int ACT, bool BIAS>
__global__ __launch_bounds__(256) void gemm_mfma(const short* __restrict__ A_b,
                                                 const short* __restrict__ Wb,
                                                 const float* __restrict__ bias,
                                                 short* __restrict__ Cb0,
                                                 int N, int K, int zsW, int zsC) {
    const short* W = Wb + (size_t)blockIdx.z * zsW;

    __shared__ short As[2][4096];   // 128 rows x 4 chunks of 16B (swizzled slots)
    __shared__ short Ws[2][4096];

    const int bm = blockIdx.y * 128, bn = blockIdx.x * 128;
    const int tid = threadIdx.x;
    const int wv = tid >> 6, lane = tid & 63;
    const int wr = wv >> 1, wc = wv & 1;
    const int l16 = lane & 15, kqr = lane >> 4;
    (void)wv; (void)lane;

    // staging geometry: chunk c = tid + i*256 -> row r=c>>2, k-quarter q=c&3
    // written to LDS slot r*4 + (q ^ swz(r)), swz(r) = (r^(r>>2))&3
    int srow[2], sq[2], sslot[2];
#pragma unroll
    for (int i = 0; i < 2; i++) {
        const int c = tid + i * 256;
        const int r = c >> 2;
        const int q = c & 3;
        srow[i]  = r;
        sq[i]    = q;
        sslot[i] = r * 4 + (q ^ ((r ^ (r >> 2)) & 3));
    }

    f32x4 acc[4][4];
    const f32x4 zr = {0.f, 0.f, 0.f, 0.f};
#pragma unroll
    for (int i = 0; i < 4; i++)
#pragma unroll
        for (int j = 0; j < 4; j++) acc[i][j] = zr;

    const int NT = K >> 5;
    s16x8 ra[2], rw[2];

    // prologue: load tile 0, write to buf 0
#pragma unroll
    for (int i = 0; i < 2; i++) {
        ra[i] = *(const s16x8*)(A_b + (size_t)(bm + srow[i]) * K + sq[i] * 8);
        rw[i] = *(const s16x8*)(W   + (size_t)(bn + srow[i]) * K + sq[i] * 8);
    }
#pragma unroll
    for (int i = 0; i < 2; i++) {
        *(s16x8*)&As[0][sslot[i] * 8] = ra[i];
        *(s16x8*)&Ws[0][sslot[i] * 8] = rw[i];
    }
    __syncthreads();

    for (int kt = 0; kt < NT; ++kt) {
        const int buf = kt & 1;
        if (kt + 1 < NT) {
            const int ko = (kt + 1) * 32;
#pragma unroll
            for (int i = 0; i < 2; i++) {
                ra[i] = *(const s16x8*)(A_b + (size_t)(bm + srow[i]) * K + ko + sq[i] * 8);
                rw[i] = *(const s16x8*)(W   + (size_t)(bn + srow[i]) * K + ko + sq[i] * 8);
            }
        }

        s16x8 af[4], bf[4];
#pragma unroll
        for (int i = 0; i < 4; i++) {
            const int r = wr * 64 + i * 16 + l16;
            const int slot = r * 4 + (kqr ^ ((r ^ (r >> 2)) & 3));
            af[i] = *(const s16x8*)&As[buf][slot * 8];
        }
#pragma unroll
        for (int j = 0; j < 4; j++) {
            const int r = wc * 64 + j * 16 + l16;
            const int slot = r * 4 + (kqr ^ ((r ^ (r >> 2)) & 3));
            bf[j] = *(const s16x8*)&Ws[buf][slot * 8];
        }
#pragma unroll
        for (int i = 0; i < 4; i++)
#pragma unroll
            for (int j = 0; j < 4; j++)
                acc[i][j] = __builtin_amdgcn_mfma_f32_16x16x32_bf16(af[i], bf[j], acc[i][j], 0, 0, 0);

        if (kt + 1 < NT) {
            __syncthreads();   // all frag reads of buf^1 from iter kt-1 are done
#pragma unroll
            for (int i = 0; i < 2; i++) {
                *(s16x8*)&As[buf ^ 1][sslot[i] * 8] = ra[i];
                *(s16x8*)&Ws[buf ^ 1][sslot[i] * 8] = rw[i];
            }
        }
        __syncthreads();
    }

    short* Cb = Cb0 + (size_t)blockIdx.z * zsC;
#pragma unroll
    for (int i = 0; i < 4; i++) {
        const int m0 = bm + wr * 64 + i * 16 + kqr * 4;
#pragma unroll
        for (int j = 0; j < 4; j++) {
            const int n = bn + wc * 64 + j * 16 + l16;
            float bv = 0.f;
            if (BIAS) bv = bias[n];
            const f32x4 v = acc[i][j];
#pragma unroll
            for (int r = 0; r < 4; r++) {
                float o = v[r] + bv;
                if (ACT == 1) o = 0.5f * o * (1.f + erff(o * 0.70710678118654752f));
                Cb[(size_t)(m0 + r) * N + n] = f2bf(o);
            }
        }
    }
}

// ---------------------------------------------------------------------------
// Fused gate + surprise + fast/slow chunked delta scan. One block per (b,h),
// 256 threads. Inputs q/k/v/g are bf16. During staging: vg = v*sigmoid(g);
// s = sigmoid(10*(k.swK + vg.swV + sb)) via 8-lane shfl reduce.
// State: thread (d=tid>>3, e4=(tid&7)*4) owns 4 fast+slow pairs.
// Output: thread (l=tid>>2, e8=(tid&3)*8): o[l,e]=sum_d q[l,d]*Sc[d,e] (bf16)
// ---------------------------------------------------------------------------
__global__ __launch_bounds__(256) void delta_kernel(const short* __restrict__ qb,
                                                    const short* __restrict__ kb,
                                                    const short* __restrict__ vb,
                                                    const short* __restrict__ gb,
                                                    const float* __restrict__ surW,
                                                    const float* __restrict__ surB,
                                                    const float* __restrict__ wf,
                                                    const float* __restrict__ alpha,
                                                    int layer, short* __restrict__ ob) {
    const int bh = blockIdx.x;
    const int b = bh / H_, h = bh % H_;
    const int tid = threadIdx.x;
    const float wfa = wf[layer * 2 + 0], wsa = wf[layer * 2 + 1];
    const float a = 1.f / (1.f + expf(-alpha[layer]));
    const float sbias = surB[0];

    __shared__ float qS[CH_][36], kS[CH_][36], vS[CH_][36];
    __shared__ float s2S[CH_];
    __shared__ float Sc[DH_][36];
    __shared__ float swS[64];

    if (tid < 64) swS[tid] = surW[tid];
    __syncthreads();

    const int d  = tid >> 3;          // 0..31
    const int e4 = (tid & 7) * 4;     // 0,4,..,28
    const int lo = tid >> 2;          // 0..63
    const int e8 = (tid & 3) * 8;     // 0,8,16,24

    float sf[4] = {0.f, 0.f, 0.f, 0.f};
    float ss[4] = {0.f, 0.f, 0.f, 0.f};

    const size_t base = ((size_t)b * L_) * D_ + (size_t)h * DH_;

    for (int c = 0; c < L_ / CH_; c++) {
        const int l0 = c * CH_;
        // stage q/k/vg chunk (64x32) + compute surprise s inline
#pragma unroll
        for (int i = 0; i < 2; i++) {
            const int c4 = tid + i * 256;          // 4-elem chunk id 0..511
            const int ll = c4 >> 3, dd4 = (c4 & 7) * 4;
            const size_t g = base + (size_t)(l0 + ll) * D_ + dd4;
            const s16x4 q4 = *(const s16x4*)(qb + g);
            const s16x4 k4 = *(const s16x4*)(kb + g);
            const s16x4 v4 = *(const s16x4*)(vb + g);
            const s16x4 g4 = *(const s16x4*)(gb + g);
            float p = 0.f;
#pragma unroll
            for (int j = 0; j < 4; j++) {
                const float kf = bf2f(k4[j]);
                const float gv = bf2f(g4[j]);
                const float vg = bf2f(v4[j]) / (1.f + expf(-gv));
                qS[ll][dd4 + j] = bf2f(q4[j]);
                kS[ll][dd4 + j] = kf;
                vS[ll][dd4 + j] = vg;
                p += kf * swS[dd4 + j] + vg * swS[32 + dd4 + j];
            }
            p += __shfl_xor(p, 1);
            p += __shfl_xor(p, 2);
            p += __shfl_xor(p, 4);
            if ((tid & 7) == 0) {
                const float sv = 1.f / (1.f + expf(-10.f * (p + sbias)));
                s2S[ll] = sv * sv;
            }
        }
        __syncthreads();

        // state update (decay then accumulate current chunk)
#pragma unroll
        for (int j = 0; j < 4; j++) { sf[j] *= wfa; ss[j] *= wsa; }
        for (int l = 0; l < CH_; l++) {
            const float vd = vS[l][d];
            const float s2 = s2S[l];
            const float4 k4 = *(const float4*)&kS[l][e4];
            const float kk[4] = {k4.x, k4.y, k4.z, k4.w};
#pragma unroll
            for (int j = 0; j < 4; j++) {
                const float p = vd * kk[j];
                sf[j] += p;
                ss[j] = fmaf(p, s2, ss[j]);
            }
        }
        float4 scv;
        scv.x = a * sf[0] + (1.f - a) * ss[0];
        scv.y = a * sf[1] + (1.f - a) * ss[1];
        scv.z = a * sf[2] + (1.f - a) * ss[2];
        scv.w = a * sf[3] + (1.f - a) * ss[3];
        *(float4*)&Sc[d][e4] = scv;
        __syncthreads();

        // output: o[lo, e8..e8+7] = sum_d q[lo,d] * Sc[d, e8..]
        float o8[8] = {0.f, 0.f, 0.f, 0.f, 0.f, 0.f, 0.f, 0.f};
        for (int dd = 0; dd < DH_; dd++) {
            const float qv = qS[lo][dd];
            const float4 s0 = *(const float4*)&Sc[dd][e8];
            const float4 s1 = *(const float4*)&Sc[dd][e8 + 4];
            o8[0] = fmaf(qv, s0.x, o8[0]); o8[1] = fmaf(qv, s0.y, o8[1]);
            o8[2] = fmaf(qv, s0.z, o8[2]); o8[3] = fmaf(qv, s0.w, o8[3]);
            o8[4] = fmaf(qv, s1.x, o8[4]); o8[5] = fmaf(qv, s1.y, o8[5]);
            o8[6] = fmaf(qv, s1.z, o8[6]); o8[7] = fmaf(qv, s1.w, o8[7]);
        }
        s16x8 t;
#pragma unroll
        for (int j = 0; j < 8; j++) t[j] = f2bf(o8[j]);
        *(s16x8*)(ob + base + (size_t)(l0 + lo) * D_ + e8) = t;
        __syncthreads();
    }
}

// ---------------------------------------------------------------------------
// Masked mean pool, stage 1: partial sums over 64-token chunks.
// grid = B*8, 384 threads. partial[(b*8+c)*D + d]; maskp[b*8+c].
// ---------------------------------------------------------------------------
__global__ __launch_bounds__(384) void pool_partial_kernel(
        const float* __restrict__ x, const int* __restrict__ mask,
        float* __restrict__ partial, float* __restrict__ maskp) {
    const int b  = blockIdx.x >> 3;
    const int ch = blockIdx.x & 7;
    const int dd = threadIdx.x;
    const int lb = ch * 64;
    float sum = 0.f;
    for (int l = 0; l < 64; l++) {
        const float m = (float)mask[b * L_ + lb + l];
        sum = fmaf(x[((size_t)(b * L_ + lb + l)) * D_ + dd], m, sum);
    }
    partial[(size_t)blockIdx.x * D_ + dd] = sum;
    if (dd < 64) {
        float mm = (float)mask[b * L_ + lb + dd];
#pragma unroll
        for (int o = 32; o > 0; o >>= 1) mm += __shfl_xor(mm, o);
        if (dd == 0) maskp[blockIdx.x] = mm;
    }
}

// ---------------------------------------------------------------------------
// Masked mean pool, stage 2: combine 8 partials, L2 normalize.
// grid = B, 384 threads.
// ---------------------------------------------------------------------------
__global__ __launch_bounds__(384) void pool_finalize_kernel(
        const float* __restrict__ partial, const float* __restrict__ maskp,
        float* __restrict__ out) {
    const int b  = blockIdx.x;
    const int dd = threadIdx.x;
    float sum = 0.f, msum = 0.f;
#pragma unroll
    for (int c = 0; c < 8; c++) {
        sum  += partial[(size_t)(b * 8 + c) * D_ + dd];
        msum += maskp[b * 8 + c];
    }
    const float emb = sum / fmaxf(msum, 1e-9f);

    __shared__ float red[6];
    __shared__ float scale;
    float q = emb * emb;
#pragma unroll
    for (int o = 32; o > 0; o >>= 1) q += __shfl_down(q, o);
    if ((dd & 63) == 0) red[dd >> 6] = q;
    __syncthreads();
    if (dd == 0) {
        float t = 0.f;
        for (int i = 0; i < 6; i++) t += red[i];
        scale = 1.f / fmaxf(sqrtf(t), 1e-12f);
    }
    __syncthreads();
    out[(size_t)b * D_ + dd] = emb * scale;
}

// ---------------------------------------------------------------------------
extern "C" void kernel_launch(void* const* d_in, const int* in_sizes, int n_in,
                              void* d_out, int out_size, void* d_ws, size_t ws_size,
                              hipStream_t stream) {
    (void)in_sizes; (void)n_in; (void)out_size; (void)ws_size;

    const int*   ids   = (const int*)d_in[0];
    const int*   mask  = (const int*)d_in[1];
    const float* wemb  = (const float*)d_in[2];
    const float* pemb  = (const float*)d_in[3];
    const float* temb  = (const float*)d_in[4];
    const float* elnw  = (const float*)d_in[5];
    const float* elnb  = (const float*)d_in[6];
    const float* qW    = (const float*)d_in[7];
    const float* kW    = (const float*)d_in[8];
    const float* vW    = (const float*)d_in[9];
    const float* oW    = (const float*)d_in[10];
    const float* gW    = (const float*)d_in[11];
    const float* convW = (const float*)d_in[12];
    const float* convB = (const float*)d_in[13];
    const float* fdec  = (const float*)d_in[14];
    const float* sdec  = (const float*)d_in[15];
    const float* surW  = (const float*)d_in[16];
    const float* surB  = (const float*)d_in[17];
    const float* alpha = (const float*)d_in[18];
    const float* ln1w  = (const float*)d_in[19];
    const float* ln1b  = (const float*)d_in[20];
    const float* fW1   = (const float*)d_in[21];
    const float* fB1   = (const float*)d_in[22];
    const float* fW2   = (const float*)d_in[23];
    const float* fB2   = (const float*)d_in[24];
    const float* ln2w  = (const float*)d_in[25];
    const float* ln2b  = (const float*)d_in[26];

    // Workspace layout (~225 MiB total)
    float* x     = (float*)d_ws;                       // MT*D f32
    float* wfp   = x + (size_t)MT * D_;                // 16 f32
    float* pp    = wfp + 16;                           // B*8*D f32 pool partials
    float* mp    = pp + (size_t)B_ * 8 * D_;           // B*8 f32 mask partials
    short* qkvg  = (short*)(mp + B_ * 8);              // 4*MT*D bf16 (q|k|v|g; reused: attn, FFN h)
    short* xb    = qkvg + (size_t)4 * MT * D_;         // MT*D bf16 (LN'd x shadow)
    short* xcb   = xb + (size_t)MT * D_;               // MT*D bf16 (conv out / delta out / ffn2 out)
    short* wqkvg = xcb + (size_t)MT * D_;              // NL*4*DD bf16
    short* wo    = wqkvg + (size_t)NL_ * 4 * DD;       // NL*DD bf16
    short* wf1   = wo + (size_t)NL_ * DD;              // NL*FF*D bf16
    short* wf2   = wf1 + (size_t)NL_ * FF_ * D_;       // NL*FF*D bf16

    short* q16 = qkvg;
    short* k16 = q16 + (size_t)MT * D_;
    short* v16 = k16 + (size_t)MT * D_;
    short* g16 = v16 + (size_t)MT * D_;
    short* attn = qkvg;                // o-proj out (bf16) reuses q region (dead after delta)
    short* hb   = qkvg;                // FFN hidden (MT x FF bf16) = whole qkvg region
    short* dob  = xcb;                 // delta output (bf16) reuses conv buffer

    // weight conversion (every call; ~23MB, negligible)
    cvt4_kernel<<<NL_ * DD / 8 / 256, 256, 0, stream>>>(qW, kW, vW, gW, wqkvg);
    cvt_kernel<<<NL_ * DD / 8 / 256, 256, 0, stream>>>(oW, wo, NL_ * DD / 8);
    cvt_kernel<<<NL_ * FF_ * D_ / 8 / 256, 256, 0, stream>>>(fW1, wf1, NL_ * FF_ * D_ / 8);
    cvt_kernel<<<NL_ * FF_ * D_ / 8 / 256, 256, 0, stream>>>(fW2, wf2, NL_ * FF_ * D_ / 8);

    embed_ln_kernel<<<MT / 4, 256, 0, stream>>>(ids, wemb, pemb, temb, elnw, elnb, x, xb);
    wfac_kernel<<<NL_ * 2, 384, 0, stream>>>(fdec, sdec, wfp);

    const dim3 g1(D_ / 128, MT / 128, 1);    // N=384
    const dim3 g2(FF_ / 128, MT / 128, 1);   // N=1536
    const dim3 gq(D_ / 128, MT / 128, 4);    // fused qkvg

    for (int i = 0; i < NL_; i++) {
        conv_silu_kernel<<<(MT * D_ / 8) / 256, 256, 0, stream>>>(
            xb, convW + (size_t)i * D_ * 4, convB + (size_t)i * D_, xcb);

        // q,k,v,g = xc @ W^T  (A bf16, C bf16)
        gemm_mfma<0, false><<<gq, 256, 0, stream>>>(
            xcb, wqkvg + (size_t)i * 4 * DD, nullptr, qkvg, D_, D_, DD, MT * D_);

        // fused gate + surprise + delta scan (reads bf16 q,k,v,g)
        delta_kernel<<<B_ * H_, 256, 0, stream>>>(
            q16, k16, v16, g16, surW + (size_t)i * 2 * DH_, surB + i, wfp, alpha, i, dob);

        // attn = delta_out @ oW^T  (C bf16 -> attn, q region dead)
        gemm_mfma<0, false><<<g1, 256, 0, stream>>>(
            dob, wo + (size_t)i * DD, nullptr, attn, D_, D_, 0, 0);
        ln_res_kernel<<<MT / 4, 256, 0, stream>>>(attn, x, xb, ln1w + (size_t)i * D_, ln1b + (size_t)i * D_);

        // h = gelu(xb @ fW1^T + b1)  (C bf16 -> hb, attn dead)
        gemm_mfma<1, true><<<g2, 256, 0, stream>>>(
            xb, wf1 + (size_t)i * FF_ * D_, fB1 + (size_t)i * FF_, hb, FF_, D_, 0, 0);
        // y = h @ fW2^T + b2  (C bf16 -> xcb, delta out dead)
        gemm_mfma<0, true><<<g1, 256, 0, stream>>>(
            hb, wf2 + (size_t)i * FF_ * D_, fB2 + (size_t)i * D_, xcb, D_, FF_, 0, 0);
        ln_res_kernel<<<MT / 4, 256, 0, stream>>>(xcb, x, xb, ln2w + (size_t)i * D_, ln2b + (size_t)i * D_);
    }

    pool_partial_kernel<<<B_ * 8, 384, 0, stream>>>(x, mask, pp, mp);
    pool_finalize_kernel<<<B_, 384, 0, stream>>>(pp, mp, (float*)d_out);
}

// Round 10
// 2838.254 us; speedup vs baseline: 1.0044x; 1.0044x over previous
//
#include <hip/hip_runtime.h>
#include <hip/hip_bf16.h>
#include <math.h>

// Problem constants (match reference)
constexpr int B_  = 64;
constexpr int L_  = 512;
constexpr int D_  = 384;
constexpr int H_  = 12;
constexpr int DH_ = 32;
constexpr int NL_ = 6;
constexpr int FF_ = 1536;
constexpr int CH_ = 64;
constexpr int MT  = B_ * L_;       // 32768 tokens
constexpr int DD  = D_ * D_;       // 147456
constexpr int TS  = 4 * D_;        // 1536, token stride of merged qkvg

typedef float f32x4 __attribute__((ext_vector_type(4)));
typedef short s16x8 __attribute__((ext_vector_type(8)));
typedef short s16x4 __attribute__((ext_vector_type(4)));

// round-to-nearest-even f32 -> bf16 bits
__device__ __forceinline__ short f2bf(float f) {
    unsigned u = __float_as_uint(f);
    unsigned r = (u + 0x7fffu + ((u >> 16) & 1u)) >> 16;
    return (short)r;
}
__device__ __forceinline__ float bf2f(short s) {
    unsigned u = ((unsigned)(unsigned short)s) << 16;
    return __uint_as_float(u);
}

// async global->LDS, 16B per lane; LDS dest is wave-uniform base
// (HW writes base + lane*16). Source address is per-lane (carries swizzle).
__device__ __forceinline__ void gl_lds16(const void* g, void* l) {
    __builtin_amdgcn_global_load_lds((const __attribute__((address_space(1))) void*)g,
                                     (__attribute__((address_space(3))) void*)l, 16, 0, 0);
}

// ---------------------------------------------------------------------------
// Weight conversion: fp32 -> bf16, 8 elems/thread
// ---------------------------------------------------------------------------
__global__ void cvt_kernel(const float* __restrict__ src, short* __restrict__ dst, int n8) {
    int i = blockIdx.x * 256 + threadIdx.x;
    if (i >= n8) return;
    const float4 lo = *(const float4*)(src + (size_t)i * 8);
    const float4 hi = *(const float4*)(src + (size_t)i * 8 + 4);
    s16x8 t;
    t[0] = f2bf(lo.x); t[1] = f2bf(lo.y); t[2] = f2bf(lo.z); t[3] = f2bf(lo.w);
    t[4] = f2bf(hi.x); t[5] = f2bf(hi.y); t[6] = f2bf(hi.z); t[7] = f2bf(hi.w);
    *(s16x8*)(dst + (size_t)i * 8) = t;
}

// q/k/v/g weights -> interleaved [layer][4][DD] bf16 (per layer = (1536,384) row-major)
__global__ void cvt4_kernel(const float* __restrict__ q, const float* __restrict__ k,
                            const float* __restrict__ v, const float* __restrict__ g,
                            short* __restrict__ dst) {
    int i = blockIdx.x * 256 + threadIdx.x;   // over NL*DD/8
    if (i >= NL_ * DD / 8) return;
    const int l = i / (DD / 8), r = i - l * (DD / 8);
    const float* srcs[4] = {q, k, v, g};
#pragma unroll
    for (int w = 0; w < 4; w++) {
        const float4 lo = *(const float4*)(srcs[w] + (size_t)i * 8);
        const float4 hi = *(const float4*)(srcs[w] + (size_t)i * 8 + 4);
        s16x8 t;
        t[0] = f2bf(lo.x); t[1] = f2bf(lo.y); t[2] = f2bf(lo.z); t[3] = f2bf(lo.w);
        t[4] = f2bf(hi.x); t[5] = f2bf(hi.y); t[6] = f2bf(hi.z); t[7] = f2bf(hi.w);
        *(s16x8*)(dst + ((size_t)(l * 4 + w) * DD) + (size_t)r * 8) = t;
    }
}

// ---------------------------------------------------------------------------
// Embedding + LayerNorm, wave-per-token (4 tokens / 256-thread block).
// Writes fp32 x and bf16 shadow xb.
// ---------------------------------------------------------------------------
__global__ __launch_bounds__(256) void embed_ln_kernel(
        const int* __restrict__ ids, const float* __restrict__ wemb,
        const float* __restrict__ pemb, const float* __restrict__ temb,
        const float* __restrict__ w, const float* __restrict__ b,
        float* __restrict__ out, short* __restrict__ outb) {
    const int t    = blockIdx.x * 4 + (threadIdx.x >> 6);
    const int lane = threadIdx.x & 63;
    const int l    = t % L_;
    const size_t ro = (size_t)t * D_;
    const size_t wo = (size_t)ids[t] * D_;
    const size_t po = (size_t)l * D_;

    float v[6];
    float s = 0.f;
#pragma unroll
    for (int j = 0; j < 6; j++) {
        const int d = j * 64 + lane;
        v[j] = wemb[wo + d] + pemb[po + d] + temb[d];
        s += v[j];
    }
#pragma unroll
    for (int o = 32; o > 0; o >>= 1) s += __shfl_xor(s, o);
    const float m = s * (1.f / D_);
    float s2 = 0.f;
#pragma unroll
    for (int j = 0; j < 6; j++) { v[j] -= m; s2 += v[j] * v[j]; }
#pragma unroll
    for (int o = 32; o > 0; o >>= 1) s2 += __shfl_xor(s2, o);
    const float r = rsqrtf(s2 * (1.f / D_) + 1e-12f);
#pragma unroll
    for (int j = 0; j < 6; j++) {
        const int d = j * 64 + lane;
        const float o = v[j] * r * w[d] + b[d];
        out[ro + d]  = o;
        outb[ro + d] = f2bf(o);
    }
}

// ---------------------------------------------------------------------------
// x = LN(x + y), y is bf16; bf16 shadow xb. Wave-per-token, no LDS/barriers.
// ---------------------------------------------------------------------------
__global__ __launch_bounds__(256) void ln_res_kernel(
        const short* __restrict__ y, float* __restrict__ x, short* __restrict__ xb,
        const float* __restrict__ w, const float* __restrict__ b) {
    const int t    = blockIdx.x * 4 + (threadIdx.x >> 6);
    const int lane = threadIdx.x & 63;
    const size_t ro = (size_t)t * D_;

    float v[6];
    float s = 0.f;
#pragma unroll
    for (int j = 0; j < 6; j++) {
        const int d = j * 64 + lane;
        v[j] = x[ro + d] + bf2f(y[ro + d]);
        s += v[j];
    }
#pragma unroll
    for (int o = 32; o > 0; o >>= 1) s += __shfl_xor(s, o);
    const float m = s * (1.f / D_);
    float s2 = 0.f;
#pragma unroll
    for (int j = 0; j < 6; j++) { v[j] -= m; s2 += v[j] * v[j]; }
#pragma unroll
    for (int o = 32; o > 0; o >>= 1) s2 += __shfl_xor(s2, o);
    const float r = rsqrtf(s2 * (1.f / D_) + 1e-12f);
#pragma unroll
    for (int j = 0; j < 6; j++) {
        const int d = j * 64 + lane;
        const float o = v[j] * r * w[d] + b[d];
        x[ro + d]  = o;
        xb[ro + d] = f2bf(o);
    }
}

// ---------------------------------------------------------------------------
// wfac[l][which] = mean(sigmoid(decay))^64   (12 blocks, 384 threads)
// ---------------------------------------------------------------------------
__global__ void wfac_kernel(const float* __restrict__ fdec, const float* __restrict__ sdec,
                            float* __restrict__ wf) {
    const int l     = blockIdx.x >> 1;
    const int which = blockIdx.x & 1;
    const float* p  = (which ? sdec : fdec) + (size_t)l * H_ * DH_;
    float v = 1.f / (1.f + expf(-p[threadIdx.x]));
    __shared__ float red[6];
#pragma unroll
    for (int o = 32; o > 0; o >>= 1) v += __shfl_down(v, o);
    if ((threadIdx.x & 63) == 0) red[threadIdx.x >> 6] = v;
    __syncthreads();
    if (threadIdx.x == 0) {
        float s = 0.f;
        for (int i = 0; i < 6; i++) s += red[i];
        float m = s / (float)(H_ * DH_);
        for (int i = 0; i < 6; i++) m = m * m;   // m^64
        wf[l * 2 + which] = m;
    }
}

// ---------------------------------------------------------------------------
// Depthwise conv1d (k=4, pad=2, truncate to L) + bias + SiLU. bf16 in/out.
// Vectorized: each thread owns 8 consecutive d (short8 loads/stores).
// ---------------------------------------------------------------------------
__global__ __launch_bounds__(256) void conv_silu_kernel(
        const short* __restrict__ xb, const float* __restrict__ cw,
        const float* __restrict__ cb, short* __restrict__ out) {
    const int i8 = blockIdx.x * 256 + threadIdx.x;   // over MT*D/8
    const int d8 = (i8 * 8) % D_;
    const int bl = (i8 * 8) / D_;
    const int l  = bl % L_;

    float acc[8];
#pragma unroll
    for (int jj = 0; jj < 8; jj++) acc[jj] = cb[d8 + jj];

    const short* xrow = xb + (size_t)(bl - l) * D_ + d8;
#pragma unroll
    for (int j = 0; j < 4; j++) {
        const int t = l + j - 2;
        if (t >= 0 && t < L_) {
            const s16x8 xv = *(const s16x8*)(xrow + (size_t)t * D_);
#pragma unroll
            for (int jj = 0; jj < 8; jj++)
                acc[jj] = fmaf(bf2f(xv[jj]), cw[(d8 + jj) * 4 + j], acc[jj]);
        }
    }
    s16x8 o;
#pragma unroll
    for (int jj = 0; jj < 8; jj++) {
        const float sv = acc[jj] / (1.f + expf(-acc[jj]));   // SiLU
        o[jj] = f2bf(sv);
    }
    *(s16x8*)(out + (size_t)i8 * 8) = o;
}

// ---------------------------------------------------------------------------
// MFMA bf16 GEMM: C[m,n] = bf16( act( sum_k A[m,k]*W[n,k] + bias[n] ) )
// A: (M,K) bf16; W: (N,K) bf16 row-major. 128x128 tile, BK=32,
// 256 thr = 4 waves (2x2), 4x4 16x16x32 frags/wave.
// Staging via global_load_lds width=16 (m97 path): LDS is linear 16B slots,
// XOR swizzle carried in the per-lane GLOBAL source address; fragment reads
// apply the same involution (both-sides-or-neither, rule #21).
// Double-buffered, ONE barrier per K-tile (buf^1 readers finished at the
// previous barrier; __syncthreads' vmcnt drain publishes the async loads).
// ---------------------------------------------------------------------------
template <int ACT, bool BIAS>
__global__ __launch_bounds__(256) void gemm_mfma(const short* __restrict__ A_b,
                                                 const short* __restrict__ W,
                                                 const float* __restrict__ bias,
                                                 short* __restrict__ Cb,
                                                 int N, int K) {
    __shared__ short As[2][4096];   // 128 rows x 4 chunks of 16B
    __shared__ short Ws[2][4096];

    const int bm = blockIdx.y * 128, bn = blockIdx.x * 128;
    const int tid = threadIdx.x;
    const int wv = tid >> 6, lane = tid & 63;
    const int wr = wv >> 1, wc = wv & 1;
    const int l16 = lane & 15, kqr = lane >> 4;

    // staging geometry: 16B chunk c = tid + i*256 -> row r=c>>2, swizzled
    // global k-quarter skq = (c&3) ^ swz(r), swz(r) = (r^(r>>2))&3
    int srow[2], skq[2];
#pragma unroll
    for (int i = 0; i < 2; i++) {
        const int c = tid + i * 256;
        const int r = c >> 2;
        srow[i] = r;
        skq[i] = (c & 3) ^ ((r ^ (r >> 2)) & 3);
    }

    f32x4 acc[4][4];
    const f32x4 zr = {0.f, 0.f, 0.f, 0.f};
#pragma unroll
    for (int i = 0; i < 4; i++)
#pragma unroll
        for (int j = 0; j < 4; j++) acc[i][j] = zr;

    const int NT = K >> 5;

    // prologue: stage tile 0 into buf 0
#pragma unroll
    for (int i = 0; i < 2; i++) {
        short* la = &As[0][(wv * 64 + i * 256) * 8];   // wave-uniform base
        short* lw = &Ws[0][(wv * 64 + i * 256) * 8];
        gl_lds16(A_b + (size_t)(bm + srow[i]) * K + skq[i] * 8, la);
        gl_lds16(W   + (size_t)(bn + srow[i]) * K + skq[i] * 8, lw);
    }
    __syncthreads();

    for (int kt = 0; kt < NT; ++kt) {
        const int buf = kt & 1;
        if (kt + 1 < NT) {
            const int ko = (kt + 1) * 32;
#pragma unroll
            for (int i = 0; i < 2; i++) {
                short* la = &As[buf ^ 1][(wv * 64 + i * 256) * 8];
                short* lw = &Ws[buf ^ 1][(wv * 64 + i * 256) * 8];
                gl_lds16(A_b + (size_t)(bm + srow[i]) * K + ko + skq[i] * 8, la);
                gl_lds16(W   + (size_t)(bn + srow[i]) * K + ko + skq[i] * 8, lw);
            }
        }

        s16x8 af[4], bf[4];
#pragma unroll
        for (int i = 0; i < 4; i++) {
            const int r = wr * 64 + i * 16 + l16;
            const int slot = r * 4 + (kqr ^ ((r ^ (r >> 2)) & 3));
            af[i] = *(const s16x8*)&As[buf][slot * 8];
        }
#pragma unroll
        for (int j = 0; j < 4; j++) {
            const int r = wc * 64 + j * 16 + l16;
            const int slot = r * 4 + (kqr ^ ((r ^ (r >> 2)) & 3));
            bf[j] = *(const s16x8*)&Ws[buf][slot * 8];
        }
#pragma unroll
        for (int i = 0; i < 4; i++)
#pragma unroll
            for (int j = 0; j < 4; j++)
                acc[i][j] = __builtin_amdgcn_mfma_f32_16x16x32_bf16(af[i], bf[j], acc[i][j], 0, 0, 0);

        __syncthreads();
    }

#pragma unroll
    for (int i = 0; i < 4; i++) {
        const int m0 = bm + wr * 64 + i * 16 + kqr * 4;
#pragma unroll
        for (int j = 0; j < 4; j++) {
            const int n = bn + wc * 64 + j * 16 + l16;
            float bv = 0.f;
            if (BIAS) bv = bias[n];
            const f32x4 v = acc[i][j];
#pragma unroll
            for (int r = 0; r < 4; r++) {
                float o = v[r] + bv;
                if (ACT == 1) o = 0.5f * o * (1.f + erff(o * 0.70710678118654752f));
                Cb[(size_t)(m0 + r) * N + n] = f2bf(o);
            }
        }
    }
}

// ---------------------------------------------------------------------------
// Fused gate + surprise + fast/slow chunked delta scan. One block per (b,h),
// 256 threads. Input is the MERGED qkvg tensor: token stride TS=1536,
// q at +0, k at +384, v at +768, g at +1152. During staging:
// vg = v*sigmoid(g); s = sigmoid(10*(k.swK + vg.swV + sb)) via 8-lane shfl.
// State: thread (d=tid>>3, e4=(tid&7)*4) owns 4 fast+slow pairs.
// Output: thread (l=tid>>2, e8=(tid&3)*8): o[l,e]=sum_d q[l,d]*Sc[d,e] (bf16)
// ---------------------------------------------------------------------------
__global__ __launch_bounds__(256) void delta_kernel(const short* __restrict__ qkvgb,
                                                    const float* __restrict__ surW,
                                                    const float* __restrict__ surB,
                                                    const float* __restrict__ wf,
                                                    const float* __restrict__ alpha,
                                                    int layer, short* __restrict__ ob) {
    const int bh = blockIdx.x;
    const int b = bh / H_, h = bh % H_;
    const int tid = threadIdx.x;
    const float wfa = wf[layer * 2 + 0], wsa = wf[layer * 2 + 1];
    const float a = 1.f / (1.f + expf(-alpha[layer]));
    const float sbias = surB[0];

    __shared__ float qS[CH_][36], kS[CH_][36], vS[CH_][36];
    __shared__ float s2S[CH_];
    __shared__ float Sc[DH_][36];
    __shared__ float swS[64];

    if (tid < 64) swS[tid] = surW[tid];
    __syncthreads();

    const int d  = tid >> 3;          // 0..31
    const int e4 = (tid & 7) * 4;     // 0,4,..,28
    const int lo = tid >> 2;          // 0..63
    const int e8 = (tid & 3) * 8;     // 0,8,16,24

    float sf[4] = {0.f, 0.f, 0.f, 0.f};
    float ss[4] = {0.f, 0.f, 0.f, 0.f};

    const size_t obase = ((size_t)b * L_) * D_ + (size_t)h * DH_;   // output (D stride)

    for (int c = 0; c < L_ / CH_; c++) {
        const int l0 = c * CH_;
        // stage q/k/vg chunk (64x32) + compute surprise s inline
#pragma unroll
        for (int i = 0; i < 2; i++) {
            const int c4 = tid + i * 256;          // 4-elem chunk id 0..511
            const int ll = c4 >> 3, dd4 = (c4 & 7) * 4;
            const size_t g = ((size_t)(b * L_) + l0 + ll) * TS + h * DH_ + dd4;
            const s16x4 q4 = *(const s16x4*)(qkvgb + g);
            const s16x4 k4 = *(const s16x4*)(qkvgb + g + D_);
            const s16x4 v4 = *(const s16x4*)(qkvgb + g + 2 * D_);
            const s16x4 g4 = *(const s16x4*)(qkvgb + g + 3 * D_);
            float p = 0.f;
#pragma unroll
            for (int j = 0; j < 4; j++) {
                const float kf = bf2f(k4[j]);
                const float gv = bf2f(g4[j]);
                const float vg = bf2f(v4[j]) / (1.f + expf(-gv));
                qS[ll][dd4 + j] = bf2f(q4[j]);
                kS[ll][dd4 + j] = kf;
                vS[ll][dd4 + j] = vg;
                p += kf * swS[dd4 + j] + vg * swS[32 + dd4 + j];
            }
            p += __shfl_xor(p, 1);
            p += __shfl_xor(p, 2);
            p += __shfl_xor(p, 4);
            if ((tid & 7) == 0) {
                const float sv = 1.f / (1.f + expf(-10.f * (p + sbias)));
                s2S[ll] = sv * sv;
            }
        }
        __syncthreads();

        // state update (decay then accumulate current chunk)
#pragma unroll
        for (int j = 0; j < 4; j++) { sf[j] *= wfa; ss[j] *= wsa; }
        for (int l = 0; l < CH_; l++) {
            const float vd = vS[l][d];
            const float s2 = s2S[l];
            const float4 k4 = *(const float4*)&kS[l][e4];
            const float kk[4] = {k4.x, k4.y, k4.z, k4.w};
#pragma unroll
            for (int j = 0; j < 4; j++) {
                const float p = vd * kk[j];
                sf[j] += p;
                ss[j] = fmaf(p, s2, ss[j]);
            }
        }
        float4 scv;
        scv.x = a * sf[0] + (1.f - a) * ss[0];
        scv.y = a * sf[1] + (1.f - a) * ss[1];
        scv.z = a * sf[2] + (1.f - a) * ss[2];
        scv.w = a * sf[3] + (1.f - a) * ss[3];
        *(float4*)&Sc[d][e4] = scv;
        __syncthreads();

        // output: o[lo, e8..e8+7] = sum_d q[lo,d] * Sc[d, e8..]
        float o8[8] = {0.f, 0.f, 0.f, 0.f, 0.f, 0.f, 0.f, 0.f};
        for (int dd = 0; dd < DH_; dd++) {
            const float qv = qS[lo][dd];
            const float4 s0 = *(const float4*)&Sc[dd][e8];
            const float4 s1 = *(const float4*)&Sc[dd][e8 + 4];
            o8[0] = fmaf(qv, s0.x, o8[0]); o8[1] = fmaf(qv, s0.y, o8[1]);
            o8[2] = fmaf(qv, s0.z, o8[2]); o8[3] = fmaf(qv, s0.w, o8[3]);
            o8[4] = fmaf(qv, s1.x, o8[4]); o8[5] = fmaf(qv, s1.y, o8[5]);
            o8[6] = fmaf(qv, s1.z, o8[6]); o8[7] = fmaf(qv, s1.w, o8[7]);
        }
        s16x8 t;
#pragma unroll
        for (int j = 0; j < 8; j++) t[j] = f2bf(o8[j]);
        *(s16x8*)(ob + obase + (size_t)(l0 + lo) * D_ + e8) = t;
        __syncthreads();
    }
}

// ---------------------------------------------------------------------------
// Masked mean pool, stage 1: partial sums over 64-token chunks.
// grid = B*8, 384 threads. partial[(b*8+c)*D + d]; maskp[b*8+c].
// ---------------------------------------------------------------------------
__global__ __launch_bounds__(384) void pool_partial_kernel(
        const float* __restrict__ x, const int* __restrict__ mask,
        float* __restrict__ partial, float* __restrict__ maskp) {
    const int b  = blockIdx.x >> 3;
    const int ch = blockIdx.x & 7;
    const int dd = threadIdx.x;
    const int lb = ch * 64;
    float sum = 0.f;
    for (int l = 0; l < 64; l++) {
        const float m = (float)mask[b * L_ + lb + l];
        sum = fmaf(x[((size_t)(b * L_ + lb + l)) * D_ + dd], m, sum);
    }
    partial[(size_t)blockIdx.x * D_ + dd] = sum;
    if (dd < 64) {
        float mm = (float)mask[b * L_ + lb + dd];
#pragma unroll
        for (int o = 32; o > 0; o >>= 1) mm += __shfl_xor(mm, o);
        if (dd == 0) maskp[blockIdx.x] = mm;
    }
}

// ---------------------------------------------------------------------------
// Masked mean pool, stage 2: combine 8 partials, L2 normalize.
// grid = B, 384 threads.
// ---------------------------------------------------------------------------
__global__ __launch_bounds__(384) void pool_finalize_kernel(
        const float* __restrict__ partial, const float* __restrict__ maskp,
        float* __restrict__ out) {
    const int b  = blockIdx.x;
    const int dd = threadIdx.x;
    float sum = 0.f, msum = 0.f;
#pragma unroll
    for (int c = 0; c < 8; c++) {
        sum  += partial[(size_t)(b * 8 + c) * D_ + dd];
        msum += maskp[b * 8 + c];
    }
    const float emb = sum / fmaxf(msum, 1e-9f);

    __shared__ float red[6];
    __shared__ float scale;
    float q = emb * emb;
#pragma unroll
    for (int o = 32; o > 0; o >>= 1) q += __shfl_down(q, o);
    if ((dd & 63) == 0) red[dd >> 6] = q;
    __syncthreads();
    if (dd == 0) {
        float t = 0.f;
        for (int i = 0; i < 6; i++) t += red[i];
        scale = 1.f / fmaxf(sqrtf(t), 1e-12f);
    }
    __syncthreads();
    out[(size_t)b * D_ + dd] = emb * scale;
}

// ---------------------------------------------------------------------------
extern "C" void kernel_launch(void* const* d_in, const int* in_sizes, int n_in,
                              void* d_out, int out_size, void* d_ws, size_t ws_size,
                              hipStream_t stream) {
    (void)in_sizes; (void)n_in; (void)out_size; (void)ws_size;

    const int*   ids   = (const int*)d_in[0];
    const int*   mask  = (const int*)d_in[1];
    const float* wemb  = (const float*)d_in[2];
    const float* pemb  = (const float*)d_in[3];
    const float* temb  = (const float*)d_in[4];
    const float* elnw  = (const float*)d_in[5];
    const float* elnb  = (const float*)d_in[6];
    const float* qW    = (const float*)d_in[7];
    const float* kW    = (const float*)d_in[8];
    const float* vW    = (const float*)d_in[9];
    const float* oW    = (const float*)d_in[10];
    const float* gW    = (const float*)d_in[11];
    const float* convW = (const float*)d_in[12];
    const float* convB = (const float*)d_in[13];
    const float* fdec  = (const float*)d_in[14];
    const float* sdec  = (const float*)d_in[15];
    const float* surW  = (const float*)d_in[16];
    const float* surB  = (const float*)d_in[17];
    const float* alpha = (const float*)d_in[18];
    const float* ln1w  = (const float*)d_in[19];
    const float* ln1b  = (const float*)d_in[20];
    const float* fW1   = (const float*)d_in[21];
    const float* fB1   = (const float*)d_in[22];
    const float* fW2   = (const float*)d_in[23];
    const float* fB2   = (const float*)d_in[24];
    const float* ln2w  = (const float*)d_in[25];
    const float* ln2b  = (const float*)d_in[26];

    // Workspace layout (~225 MiB total)
    float* x     = (float*)d_ws;                       // MT*D f32
    float* wfp   = x + (size_t)MT * D_;                // 16 f32
    float* pp    = wfp + 16;                           // B*8*D f32 pool partials
    float* mp    = pp + (size_t)B_ * 8 * D_;           // B*8 f32 mask partials
    short* qkvg  = (short*)(mp + B_ * 8);              // MT*TS bf16 merged (reused: attn, FFN h)
    short* xb    = qkvg + (size_t)MT * TS;             // MT*D bf16 (LN'd x shadow)
    short* xcb   = xb + (size_t)MT * D_;               // MT*D bf16 (conv out / delta out / ffn2 out)
    short* wqkvg = xcb + (size_t)MT * D_;              // NL*4*DD bf16
    short* wo    = wqkvg + (size_t)NL_ * 4 * DD;       // NL*DD bf16
    short* wf1   = wo + (size_t)NL_ * DD;              // NL*FF*D bf16
    short* wf2   = wf1 + (size_t)NL_ * FF_ * D_;       // NL*FF*D bf16

    short* attn = qkvg;                // o-proj out (bf16) reuses qkvg (dead after delta)
    short* hb   = qkvg;                // FFN hidden (MT x FF bf16) = qkvg region
    short* dob  = xcb;                 // delta output (bf16) reuses conv buffer

    // weight conversion (every call; ~23MB, negligible)
    cvt4_kernel<<<NL_ * DD / 8 / 256, 256, 0, stream>>>(qW, kW, vW, gW, wqkvg);
    cvt_kernel<<<NL_ * DD / 8 / 256, 256, 0, stream>>>(oW, wo, NL_ * DD / 8);
    cvt_kernel<<<NL_ * FF_ * D_ / 8 / 256, 256, 0, stream>>>(fW1, wf1, NL_ * FF_ * D_ / 8);
    cvt_kernel<<<NL_ * FF_ * D_ / 8 / 256, 256, 0, stream>>>(fW2, wf2, NL_ * FF_ * D_ / 8);

    embed_ln_kernel<<<MT / 4, 256, 0, stream>>>(ids, wemb, pemb, temb, elnw, elnb, x, xb);
    wfac_kernel<<<NL_ * 2, 384, 0, stream>>>(fdec, sdec, wfp);

    const dim3 g1(D_ / 128, MT / 128);    // N=384
    const dim3 g2(FF_ / 128, MT / 128);   // N=1536 (merged qkvg and FFN1)

    for (int i = 0; i < NL_; i++) {
        conv_silu_kernel<<<(MT * D_ / 8) / 256, 256, 0, stream>>>(
            xb, convW + (size_t)i * D_ * 4, convB + (size_t)i * D_, xcb);

        // qkvg = xc @ Wcat^T : ONE GEMM, N=1536 (A fetched once)
        gemm_mfma<0, false><<<g2, 256, 0, stream>>>(
            xcb, wqkvg + (size_t)i * 4 * DD, nullptr, qkvg, TS, D_);

        // fused gate + surprise + delta scan (reads merged qkvg, stride 1536)
        delta_kernel<<<B_ * H_, 256, 0, stream>>>(
            qkvg, surW + (size_t)i * 2 * DH_, surB + i, wfp, alpha, i, dob);

        // attn = delta_out @ oW^T  (qkvg region dead -> attn)
        gemm_mfma<0, false><<<g1, 256, 0, stream>>>(
            dob, wo + (size_t)i * DD, nullptr, attn, D_, D_);
        ln_res_kernel<<<MT / 4, 256, 0, stream>>>(attn, x, xb, ln1w + (size_t)i * D_, ln1b + (size_t)i * D_);

        // h = gelu(xb @ fW1^T + b1)  (attn dead -> hb)
        gemm_mfma<1, true><<<g2, 256, 0, stream>>>(
            xb, wf1 + (size_t)i * FF_ * D_, fB1 + (size_t)i * FF_, hb, FF_, D_);
        // y = h @ fW2^T + b2  (delta out dead -> xcb)
        gemm_mfma<0, true><<<g1, 256, 0, stream>>>(
            hb, wf2 + (size_t)i * FF_ * D_, fB2 + (size_t)i * D_, xcb, D_, FF_);
        ln_res_kernel<<<MT / 4, 256, 0, stream>>>(xcb, x, xb, ln2w + (size_t)i * D_, ln2b + (size_t)i * D_);
    }

    pool_partial_kernel<<<B_ * 8, 384, 0, stream>>>(x, mask, pp, mp);
    pool_finalize_kernel<<<B_, 384, 0, stream>>>(pp, mp, (float*)d_out);
}